// Round 5
// baseline (136.815 us; speedup 1.0000x reference)
//
#include <hip/hip_runtime.h>
#include <hip/hip_bf16.h>
#include <math.h>

#define BATCH 512
#define FEAT  256
#define NCLS  100000
#define SCALE_ 32.0f
#define M0_    0.5f
#define MMIN_  0.25f

#define BN 128                       // classes per tile
#define NT 782                       // ceil(100000/128)
#define NBLK 256                     // persistent blocks (1/CU)
#define NPART 256                    // one partial slot per block
#define K4CHUNK 16
#define NK4 (NPART / K4CHUNK)        // 16

typedef unsigned short u16;
typedef short s16x8 __attribute__((ext_vector_type(8)));
typedef float f32x4 __attribute__((ext_vector_type(4)));

// ---- static device scratch ----
__device__ u16   g_fbf16[BATCH * FEAT];    // normalized features, bf16
__device__ float g_norms[BATCH];
__device__ float g_dot[BATCH];             // raw f32 feat . W[label]
__device__ float g_wn2[BATCH];             // ||W[label]||^2 (f32)
__device__ float g_pmax[NPART * BATCH];
__device__ float g_psum[NPART * BATCH];
__device__ float g_qm[NK4 * BATCH];
__device__ float g_qs[NK4 * BATCH];
__device__ int   g_lab32;                  // 1 if labels arrived as int32

__device__ __forceinline__ u16 f2b(float x) {
  union { float f; unsigned u; } v; v.f = x;
  unsigned r = v.u + 0x7FFFu + ((v.u >> 16) & 1u);   // RNE
  return (u16)(r >> 16);
}

// K1a: per-row feature norm; store NORMALIZED bf16 row. One wave per row.
// Block 0 wave 0 additionally detects label width (int32 vs int64).
__global__ void k1a(const float* __restrict__ feat, const int* __restrict__ labw) {
  int wid = threadIdx.x >> 6, lane = threadIdx.x & 63;
  int row = blockIdx.x * 4 + wid;
  float4 f = ((const float4*)(feat + row * FEAT))[lane];
  float ss = f.x * f.x + f.y * f.y + f.z * f.z + f.w * f.w;
  #pragma unroll
  for (int d = 1; d < 64; d <<= 1) ss += __shfl_xor(ss, d, 64);
  float nrm = sqrtf(ss);
  float inv = 1.0f / fmaxf(nrm, 1e-12f);
  ushort4 h;
  h.x = f2b(f.x * inv); h.y = f2b(f.y * inv);
  h.z = f2b(f.z * inv); h.w = f2b(f.w * inv);
  ((ushort4*)(g_fbf16 + row * FEAT))[lane] = h;
  if (lane == 0) g_norms[row] = nrm;
  if (blockIdx.x == 0 && wid == 0) {
    int odd = 0;
    #pragma unroll
    for (int k = 0; k < 4; ++k) odd |= labw[2 * (k * 64 + lane) + 1];
    unsigned long long b = __ballot(odd != 0);
    if (lane == 0) g_lab32 = (b != 0ULL) ? 1 : 0;
  }
}

// K2c: raw f32 dot(feat_i, W[label_i]) and ||W[label_i]||^2. One wave per row.
__global__ void k2c(const float* __restrict__ feat, const float* __restrict__ wmat,
                    const void* __restrict__ labels) {
  int wid = threadIdx.x >> 6, lane = threadIdx.x & 63;
  int i = blockIdx.x * 4 + wid;
  long long lab;
  if (g_lab32) lab = (long long)((const int*)labels)[i];
  else         lab = ((const long long*)labels)[i];
  float4 a = ((const float4*)(feat + i * FEAT))[lane];
  float4 b = ((const float4*)(wmat + (size_t)lab * FEAT))[lane];
  float d  = a.x * b.x + a.y * b.y + a.z * b.z + a.w * b.w;
  float bb = b.x * b.x + b.y * b.y + b.z * b.z + b.w * b.w;
  #pragma unroll
  for (int t = 1; t < 64; t <<= 1) {
    d  += __shfl_xor(d, t, 64);
    bb += __shfl_xor(bb, t, 64);
  }
  if (lane == 0) { g_dot[i] = d; g_wn2[i] = bb; }
}

// K3 (fused): persistent blocks, 1/CU. Block bid processes class tiles
// {bid, bid+256, bid+512, [bid+768]} for ALL 512 samples (features in regs,
// fr[4][8] per wave, 8 waves x 64 samples). W staged reg-path from raw f32:
// load 8 f32 of a row per lane -> row sumsq (in-lane + 5 shfl over the row's
// 32 lanes) -> normalize -> bf16 -> swizzled ds_write_b128 into dbuf LDS.
// Issue-early/consume-late (T14): half0 loads before quarters 0-1, consumed
// between; half1 before quarters 2-3, consumed after. One barrier per tile.
// Swapped MFMA (D row=class, col=sample); classes in 4 quarter-passes.

#define ISSUE_HALF(h, cb) do {                                              \
    _Pragma("unroll")                                                       \
    for (int ii = 0; ii < 4; ++ii) {                                        \
      int p2 = ((h) * 4 + ii) * 512 + tid;                                  \
      int rowL = p2 >> 5, ch = p2 & 31;                                     \
      int rg = (cb) + rowL; rg = rg < NCLS ? rg : NCLS - 1;                 \
      const float4* src = (const float4*)(wmat + (size_t)rg * FEAT + ch * 8); \
      L[ii][0] = src[0]; L[ii][1] = src[1];                                 \
    }                                                                       \
  } while (0)

#define CONSUME_HALF(h, nb) do {                                            \
    _Pragma("unroll")                                                       \
    for (int ii = 0; ii < 4; ++ii) {                                        \
      int p2 = ((h) * 4 + ii) * 512 + tid;                                  \
      int rowL = p2 >> 5, ch = p2 & 31;                                     \
      float4 a = L[ii][0], b = L[ii][1];                                    \
      float ss = a.x*a.x + a.y*a.y + a.z*a.z + a.w*a.w                      \
               + b.x*b.x + b.y*b.y + b.z*b.z + b.w*b.w;                     \
      ss += __shfl_xor(ss, 1, 64);  ss += __shfl_xor(ss, 2, 64);            \
      ss += __shfl_xor(ss, 4, 64);  ss += __shfl_xor(ss, 8, 64);            \
      ss += __shfl_xor(ss, 16, 64);                                         \
      float inv = 1.0f / fmaxf(sqrtf(ss), 1e-12f);                          \
      union { s16x8 v; u16 u[8]; } o;                                       \
      o.u[0] = f2b(a.x * inv); o.u[1] = f2b(a.y * inv);                     \
      o.u[2] = f2b(a.z * inv); o.u[3] = f2b(a.w * inv);                     \
      o.u[4] = f2b(b.x * inv); o.u[5] = f2b(b.y * inv);                     \
      o.u[6] = f2b(b.z * inv); o.u[7] = f2b(b.w * inv);                     \
      *(s16x8*)(&Ws[nb][0] + rowL * FEAT + (ch ^ (rowL & 7)) * 8) = o.v;    \
    }                                                                       \
  } while (0)

#define QUARTER(q4) do {                                                    \
    f32x4 acc[2][4];                                                        \
    _Pragma("unroll")                                                       \
    for (int cf = 0; cf < 2; ++cf)                                          \
      _Pragma("unroll")                                                     \
      for (int m = 0; m < 4; ++m)                                           \
        acc[cf][m] = f32x4{0.0f, 0.0f, 0.0f, 0.0f};                         \
    const u16* wb = &Ws[buf][0];                                            \
    _Pragma("unroll")                                                       \
    for (int c = 0; c < 8; ++c) {                                           \
      s16x8 wf[2];                                                          \
      _Pragma("unroll")                                                     \
      for (int cf = 0; cf < 2; ++cf) {                                      \
        int row = (q4) * 32 + cf * 16 + s;                                  \
        int cc = c * 4 + q;                                                 \
        wf[cf] = *(const s16x8*)(wb + row * FEAT + (cc ^ (row & 7)) * 8);   \
      }                                                                     \
      _Pragma("unroll")                                                     \
      for (int cf = 0; cf < 2; ++cf)                                        \
        _Pragma("unroll")                                                   \
        for (int m = 0; m < 4; ++m)                                         \
          acc[cf][m] = __builtin_amdgcn_mfma_f32_16x16x32_bf16(             \
              wf[cf], fr[m][c], acc[cf][m], 0, 0, 0);                       \
    }                                                                       \
    const int cbase = tile * BN + (q4) * 32;                                \
    const bool edge = (tile * BN + BN > NCLS);                              \
    _Pragma("unroll")                                                       \
    for (int m = 0; m < 4; ++m) {                                           \
      float v[8];                                                           \
      _Pragma("unroll")                                                     \
      for (int cf = 0; cf < 2; ++cf)                                        \
        _Pragma("unroll")                                                   \
        for (int r = 0; r < 4; ++r) {                                       \
          float cs_ = fminf(fmaxf(acc[cf][m][r], -CLIP), CLIP);             \
          float lv = SCALE_ * cs_;                                          \
          if (edge) {                                                       \
            int cls = cbase + cf * 16 + q * 4 + r;                          \
            if (cls >= NCLS) lv = -1e30f;                                   \
          }                                                                 \
          v[cf * 4 + r] = lv;                                               \
        }                                                                   \
      float mx = fmaxf(fmaxf(fmaxf(v[0], v[1]), fmaxf(v[2], v[3])),         \
                       fmaxf(fmaxf(v[4], v[5]), fmaxf(v[6], v[7])));        \
      mx = fmaxf(mx, __shfl_xor(mx, 16, 64));                               \
      mx = fmaxf(mx, __shfl_xor(mx, 32, 64));                               \
      float nM = fmaxf(M[m], mx);                                           \
      float sl = 0.0f;                                                      \
      _Pragma("unroll")                                                     \
      for (int j = 0; j < 8; ++j) sl += __expf(v[j] - nM);                  \
      sl += __shfl_xor(sl, 16, 64);                                         \
      sl += __shfl_xor(sl, 32, 64);                                         \
      S[m] = S[m] * __expf(M[m] - nM) + sl;                                 \
      M[m] = nM;                                                            \
    }                                                                       \
  } while (0)

__global__ __launch_bounds__(512, 2) void k3(const float* __restrict__ wmat) {
  __shared__ __align__(16) u16 Ws[2][BN * FEAT];   // 2 x 64 KB

  const int tid  = threadIdx.x;
  const int lane = tid & 63, wid = tid >> 6;
  const int s = lane & 15, q = lane >> 4;
  const int bid = blockIdx.x;
  const int niter = (bid < (NT - 3 * NBLK)) ? 4 : 3;   // bid<14 -> 4 tiles
  const float CLIP = 1.0f - 1e-7f;

  // feature fragments (B-operand): 64 samples per wave, register-resident.
  s16x8 fr[4][8];
  {
    const int srow = wid * 64;
    #pragma unroll
    for (int m = 0; m < 4; ++m)
      #pragma unroll
      for (int c = 0; c < 8; ++c)
        fr[m][c] = *(const s16x8*)(g_fbf16 + (srow + m * 16 + s) * FEAT + c * 32 + q * 8);
  }

  float M[4], S[4];
  #pragma unroll
  for (int m = 0; m < 4; ++m) { M[m] = -1e30f; S[m] = 0.0f; }

  float4 L[4][2];

  // prologue: stage tile `bid` into buf 0
  ISSUE_HALF(0, bid * BN);
  CONSUME_HALF(0, 0);
  ISSUE_HALF(1, bid * BN);
  CONSUME_HALF(1, 0);
  __syncthreads();

  int buf = 0;
  for (int t = 0; t < niter; ++t) {
    const int tile = bid + t * NBLK;
    const bool last = (t + 1 == niter);
    const int ncb = (bid + (t + 1) * NBLK) * BN;

    if (!last) ISSUE_HALF(0, ncb);
    QUARTER(0);
    QUARTER(1);
    if (!last) { CONSUME_HALF(0, buf ^ 1); ISSUE_HALF(1, ncb); }
    QUARTER(2);
    QUARTER(3);
    if (!last) CONSUME_HALF(1, buf ^ 1);
    __syncthreads();
    buf ^= 1;
  }

  // partial write: slot = bid; lanes 0..15 carry distinct samples.
  if (lane < 16) {
    #pragma unroll
    for (int m = 0; m < 4; ++m) {
      int smp = wid * 64 + m * 16 + lane;
      g_pmax[bid * BATCH + smp] = M[m];
      g_psum[bid * BATCH + smp] = S[m];
    }
  }
}

// K4a: combine 16 of the 256 partial slots per sample per block (coalesced).
__global__ __launch_bounds__(512) void k4a() {
  int i = threadIdx.x;   // sample
  int b = blockIdx.x;    // chunk of partial slots
  float M = -1e30f, S = 0.0f;
  #pragma unroll 4
  for (int p = b * K4CHUNK; p < b * K4CHUNK + K4CHUNK; ++p) {
    float m2 = g_pmax[p * BATCH + i];
    float s2 = g_psum[p * BATCH + i];
    float nM = fmaxf(M, m2);
    S = S * __expf(M - nM) + s2 * __expf(m2 - nM);
    M = nM;
  }
  g_qm[b * BATCH + i] = M;
  g_qs[b * BATCH + i] = S;
}

// K4b: chunk combine + margins (min/max of norms) + target-logit fixup +
// weighted mean.
__global__ void k4b(const float* __restrict__ wts, float* __restrict__ out) {
  int i = threadIdx.x;  // 512
  float M = -1e30f, S = 0.0f;
  #pragma unroll
  for (int t = 0; t < NK4; ++t) {
    float m2 = g_qm[t * BATCH + i];
    float s2 = g_qs[t * BATCH + i];
    float nM = fmaxf(M, m2);
    S = S * __expf(M - nM) + s2 * __expf(m2 - nM);
    M = nM;
  }
  float n = g_norms[i];
  __shared__ float smin[512], smax[512];
  smin[i] = n; smax[i] = n;
  __syncthreads();
  for (int st = 256; st > 0; st >>= 1) {
    if (i < st) {
      smin[i] = fminf(smin[i], smin[i + st]);
      smax[i] = fmaxf(smax[i], smax[i + st]);
    }
    __syncthreads();
  }
  float lo = smin[0], hi = smax[0];
  float denom = fmaxf(hi - lo, 1e-8f);
  float mg = MMIN_ + (M0_ - MMIN_) * (n - lo) / denom;
  mg = fminf(fmaxf(mg, MMIN_), M0_);

  const float CLIP = 1.0f - 1e-7f;
  float wn = fmaxf(sqrtf(g_wn2[i]), 1e-12f);
  float ct = g_dot[i] / (fmaxf(n, 1e-12f) * wn);
  ct = fminf(fmaxf(ct, -CLIP), CLIP);

  float sint = sqrtf(fmaxf(0.0f, 1.0f - ct * ct));
  float cosm = ct * cosf(mg) - sint * sinf(mg);
  float lt_old = SCALE_ * ct, lt_new = SCALE_ * cosm;
  float S2 = S - __expf(lt_old - M) + __expf(lt_new - M);
  float lse = M + logf(S2);
  float contrib = (lse - lt_new) * wts[i];
  __shared__ float sred[512];
  sred[i] = contrib;
  __syncthreads();
  for (int st = 256; st > 0; st >>= 1) {
    if (i < st) sred[i] += sred[i + st];
    __syncthreads();
  }
  if (i == 0) out[0] = sred[0] * (1.0f / (float)BATCH);
}

extern "C" void kernel_launch(void* const* d_in, const int* in_sizes, int n_in,
                              void* d_out, int out_size, void* d_ws, size_t ws_size,
                              hipStream_t stream) {
  const float* feat = (const float*)d_in[0];
  const float* wmat = (const float*)d_in[1];
  const float* wts  = (const float*)d_in[2];
  const void*  labs = d_in[3];
  float* out = (float*)d_out;

  hipLaunchKernelGGL(k1a, dim3(BATCH / 4), dim3(256), 0, stream, feat, (const int*)labs);
  hipLaunchKernelGGL(k2c, dim3(BATCH / 4), dim3(256), 0, stream, feat, wmat, labs);
  hipLaunchKernelGGL(k3,  dim3(NBLK), dim3(512), 0, stream, wmat);
  hipLaunchKernelGGL(k4a, dim3(NK4), dim3(512), 0, stream);
  hipLaunchKernelGGL(k4b, dim3(1), dim3(512), 0, stream, wts, out);
}

// Round 6
// 74.219 us; speedup vs baseline: 1.8434x; 1.8434x over previous
//
#include <hip/hip_runtime.h>
#include <hip/hip_bf16.h>
#include <math.h>

#define BATCH 512
#define FEAT  256
#define NCLS  100000
#define SCALE_ 32.0f
#define M0_    0.5f
#define MMIN_  0.25f

#define BN 128                       // classes per tile
#define NT 782                       // ceil(100000/128)
#define NBLK 256                     // persistent blocks (1/CU)
#define NPART 256                    // one partial slot per block
#define K4CHUNK 16
#define NK4 (NPART / K4CHUNK)        // 16

typedef unsigned short u16;
typedef short s16x8 __attribute__((ext_vector_type(8)));
typedef float f32x4 __attribute__((ext_vector_type(4)));

// ---- static device scratch ----
__device__ u16   g_fbf16[BATCH * FEAT];    // normalized features, bf16
__device__ float g_norms[BATCH];
__device__ float g_dot[BATCH];             // raw f32 feat . W[label]
__device__ float g_wn2[BATCH];             // ||W[label]||^2 (f32)
__device__ float g_pmax[NPART * BATCH];
__device__ float g_psum[NPART * BATCH];
__device__ float g_qm[NK4 * BATCH];
__device__ float g_qs[NK4 * BATCH];
__device__ int   g_lab32;                  // 1 if labels arrived as int32

__device__ __forceinline__ u16 f2b(float x) {
  union { float f; unsigned u; } v; v.f = x;
  unsigned r = v.u + 0x7FFFu + ((v.u >> 16) & 1u);   // RNE
  return (u16)(r >> 16);
}

// packed f32x2 -> bf16x2 (lo = a, hi = b); no builtin on gfx950 -> inline asm
__device__ __forceinline__ unsigned pkbf16(float a, float b) {
  unsigned r;
  asm("v_cvt_pk_bf16_f32 %0, %1, %2" : "=v"(r) : "v"(a), "v"(b));
  return r;
}

// K1a: per-row feature norm; store NORMALIZED bf16 row. One wave per row.
// Block 0 wave 0 additionally detects label width (int32 vs int64).
__global__ void k1a(const float* __restrict__ feat, const int* __restrict__ labw) {
  int wid = threadIdx.x >> 6, lane = threadIdx.x & 63;
  int row = blockIdx.x * 4 + wid;
  float4 f = ((const float4*)(feat + row * FEAT))[lane];
  float ss = f.x * f.x + f.y * f.y + f.z * f.z + f.w * f.w;
  #pragma unroll
  for (int d = 1; d < 64; d <<= 1) ss += __shfl_xor(ss, d, 64);
  float nrm = sqrtf(ss);
  float inv = 1.0f / fmaxf(nrm, 1e-12f);
  ushort4 h;
  h.x = f2b(f.x * inv); h.y = f2b(f.y * inv);
  h.z = f2b(f.z * inv); h.w = f2b(f.w * inv);
  ((ushort4*)(g_fbf16 + row * FEAT))[lane] = h;
  if (lane == 0) g_norms[row] = nrm;
  if (blockIdx.x == 0 && wid == 0) {
    int odd = 0;
    #pragma unroll
    for (int k = 0; k < 4; ++k) odd |= labw[2 * (k * 64 + lane) + 1];
    unsigned long long b = __ballot(odd != 0);
    if (lane == 0) g_lab32 = (b != 0ULL) ? 1 : 0;
  }
}

// K2c: raw f32 dot(feat_i, W[label_i]) and ||W[label_i]||^2. One wave per row.
__global__ void k2c(const float* __restrict__ feat, const float* __restrict__ wmat,
                    const void* __restrict__ labels) {
  int wid = threadIdx.x >> 6, lane = threadIdx.x & 63;
  int i = blockIdx.x * 4 + wid;
  long long lab;
  if (g_lab32) lab = (long long)((const int*)labels)[i];
  else         lab = ((const long long*)labels)[i];
  float4 a = ((const float4*)(feat + i * FEAT))[lane];
  float4 b = ((const float4*)(wmat + (size_t)lab * FEAT))[lane];
  float d  = a.x * b.x + a.y * b.y + a.z * b.z + a.w * b.w;
  float bb = b.x * b.x + b.y * b.y + b.z * b.z + b.w * b.w;
  #pragma unroll
  for (int t = 1; t < 64; t <<= 1) {
    d  += __shfl_xor(d, t, 64);
    bb += __shfl_xor(bb, t, 64);
  }
  if (lane == 0) { g_dot[i] = d; g_wn2[i] = bb; }
}

// K3 (fused): persistent blocks, 1/CU. Block bid processes class tiles
// {bid, bid+256, bid+512, [bid+768]} for ALL 512 samples (features in regs,
// fr[4][8] per wave, 8 waves x 64 samples). W is read RAW f32 once; each
// stage chunk (64 rows) is: 8x float4 loads/thread -> row sumsq (in-lane +
// 3 shfl over the row's 8 lanes) -> normalize -> v_cvt_pk_bf16 -> swizzled
// 16B LDS writes. Chunks are TRANSIENT (no regs held across quarters) and
// sit in the acc-dead gaps after Q0/Q1. One barrier per tile.
// Swapped MFMA (D row=class, col=sample); classes in 4 quarter-passes.

#define STAGE_CHUNK(RB, TILE, NB) do {                                      \
    int rowL_ = (RB) + (tid >> 3);                                          \
    int seg_ = (tid & 7) * 8;      /* in float4 units: 8 float4 = 32 f32 */ \
    int rg_ = (TILE) * BN + rowL_; rg_ = rg_ < NCLS ? rg_ : NCLS - 1;       \
    const float4* src_ = (const float4*)(wmat + (size_t)rg_ * FEAT) + seg_; \
    float4 v_[8];                                                           \
    _Pragma("unroll")                                                       \
    for (int k_ = 0; k_ < 8; ++k_) v_[k_] = src_[k_];                       \
    float ss_ = 0.0f;                                                       \
    _Pragma("unroll")                                                       \
    for (int k_ = 0; k_ < 8; ++k_)                                          \
      ss_ += v_[k_].x * v_[k_].x + v_[k_].y * v_[k_].y                      \
           + v_[k_].z * v_[k_].z + v_[k_].w * v_[k_].w;                     \
    ss_ += __shfl_xor(ss_, 1, 64);                                          \
    ss_ += __shfl_xor(ss_, 2, 64);                                          \
    ss_ += __shfl_xor(ss_, 4, 64);                                          \
    float inv_ = 1.0f / fmaxf(sqrtf(ss_), 1e-12f);                          \
    u16* dst_ = &Ws[NB][0] + rowL_ * FEAT;                                  \
    int ch0_ = (tid & 7) * 4;                                               \
    _Pragma("unroll")                                                       \
    for (int k_ = 0; k_ < 4; ++k_) {                                        \
      int4 w_;                                                              \
      w_.x = pkbf16(v_[2*k_].x * inv_,   v_[2*k_].y * inv_);                \
      w_.y = pkbf16(v_[2*k_].z * inv_,   v_[2*k_].w * inv_);                \
      w_.z = pkbf16(v_[2*k_+1].x * inv_, v_[2*k_+1].y * inv_);              \
      w_.w = pkbf16(v_[2*k_+1].z * inv_, v_[2*k_+1].w * inv_);              \
      *(int4*)(dst_ + ((ch0_ + k_) ^ (rowL_ & 7)) * 8) = w_;                \
    }                                                                       \
  } while (0)

#define QUARTER(q4) do {                                                    \
    f32x4 acc[2][4];                                                        \
    _Pragma("unroll")                                                       \
    for (int cf = 0; cf < 2; ++cf)                                          \
      _Pragma("unroll")                                                     \
      for (int m = 0; m < 4; ++m)                                           \
        acc[cf][m] = f32x4{0.0f, 0.0f, 0.0f, 0.0f};                         \
    const u16* wb = &Ws[buf][0];                                            \
    _Pragma("unroll")                                                       \
    for (int c = 0; c < 8; ++c) {                                           \
      s16x8 wf[2];                                                          \
      _Pragma("unroll")                                                     \
      for (int cf = 0; cf < 2; ++cf) {                                      \
        int row = (q4) * 32 + cf * 16 + s;                                  \
        int cc = c * 4 + q;                                                 \
        wf[cf] = *(const s16x8*)(wb + row * FEAT + (cc ^ (row & 7)) * 8);   \
      }                                                                     \
      _Pragma("unroll")                                                     \
      for (int cf = 0; cf < 2; ++cf)                                        \
        _Pragma("unroll")                                                   \
        for (int m = 0; m < 4; ++m)                                         \
          acc[cf][m] = __builtin_amdgcn_mfma_f32_16x16x32_bf16(             \
              wf[cf], fr[m][c], acc[cf][m], 0, 0, 0);                       \
    }                                                                       \
    const int cbase = tile * BN + (q4) * 32;                                \
    const bool edge = (tile * BN + BN > NCLS);                              \
    _Pragma("unroll")                                                       \
    for (int m = 0; m < 4; ++m) {                                           \
      float v[8];                                                           \
      _Pragma("unroll")                                                     \
      for (int cf = 0; cf < 2; ++cf)                                        \
        _Pragma("unroll")                                                   \
        for (int r = 0; r < 4; ++r) {                                       \
          float cs_ = fminf(fmaxf(acc[cf][m][r], -CLIP), CLIP);             \
          float lv = SCALE_ * cs_;                                          \
          if (edge) {                                                       \
            int cls = cbase + cf * 16 + q * 4 + r;                          \
            if (cls >= NCLS) lv = -1e30f;                                   \
          }                                                                 \
          v[cf * 4 + r] = lv;                                               \
        }                                                                   \
      float mx = fmaxf(fmaxf(fmaxf(v[0], v[1]), fmaxf(v[2], v[3])),         \
                       fmaxf(fmaxf(v[4], v[5]), fmaxf(v[6], v[7])));        \
      mx = fmaxf(mx, __shfl_xor(mx, 16, 64));                               \
      mx = fmaxf(mx, __shfl_xor(mx, 32, 64));                               \
      float nM = fmaxf(M[m], mx);                                           \
      float sl = 0.0f;                                                      \
      _Pragma("unroll")                                                     \
      for (int j = 0; j < 8; ++j) sl += __expf(v[j] - nM);                  \
      sl += __shfl_xor(sl, 16, 64);                                         \
      sl += __shfl_xor(sl, 32, 64);                                         \
      S[m] = S[m] * __expf(M[m] - nM) + sl;                                 \
      M[m] = nM;                                                            \
    }                                                                       \
  } while (0)

__global__ __launch_bounds__(512, 2) void k3(const float* __restrict__ wmat) {
  __shared__ __align__(16) u16 Ws[2][BN * FEAT];   // 2 x 64 KB

  const int tid  = threadIdx.x;
  const int lane = tid & 63, wid = tid >> 6;
  const int s = lane & 15, q = lane >> 4;
  const int bid = blockIdx.x;
  const int niter = (bid < (NT - 3 * NBLK)) ? 4 : 3;   // bid<14 -> 4 tiles
  const float CLIP = 1.0f - 1e-7f;

  // feature fragments (B-operand): 64 samples per wave, register-resident.
  s16x8 fr[4][8];
  {
    const int srow = wid * 64;
    #pragma unroll
    for (int m = 0; m < 4; ++m)
      #pragma unroll
      for (int c = 0; c < 8; ++c)
        fr[m][c] = *(const s16x8*)(g_fbf16 + (srow + m * 16 + s) * FEAT + c * 32 + q * 8);
  }

  float M[4], S[4];
  #pragma unroll
  for (int m = 0; m < 4; ++m) { M[m] = -1e30f; S[m] = 0.0f; }

  // prologue: stage tile `bid` into buf 0
  STAGE_CHUNK(0,  bid, 0);
  STAGE_CHUNK(64, bid, 0);
  __syncthreads();

  int buf = 0;
  for (int t = 0; t < niter; ++t) {
    const int tile = bid + t * NBLK;
    const bool last = (t + 1 == niter);
    const int ntile = bid + (t + 1) * NBLK;

    QUARTER(0);
    if (!last) STAGE_CHUNK(0, ntile, buf ^ 1);
    QUARTER(1);
    if (!last) STAGE_CHUNK(64, ntile, buf ^ 1);
    QUARTER(2);
    QUARTER(3);
    __syncthreads();
    buf ^= 1;
  }

  // partial write: slot = bid; lanes 0..15 carry distinct samples.
  if (lane < 16) {
    #pragma unroll
    for (int m = 0; m < 4; ++m) {
      int smp = wid * 64 + m * 16 + lane;
      g_pmax[bid * BATCH + smp] = M[m];
      g_psum[bid * BATCH + smp] = S[m];
    }
  }
}

// K4a: combine 16 of the 256 partial slots per sample per block (coalesced).
__global__ __launch_bounds__(512) void k4a() {
  int i = threadIdx.x;   // sample
  int b = blockIdx.x;    // chunk of partial slots
  float M = -1e30f, S = 0.0f;
  #pragma unroll 4
  for (int p = b * K4CHUNK; p < b * K4CHUNK + K4CHUNK; ++p) {
    float m2 = g_pmax[p * BATCH + i];
    float s2 = g_psum[p * BATCH + i];
    float nM = fmaxf(M, m2);
    S = S * __expf(M - nM) + s2 * __expf(m2 - nM);
    M = nM;
  }
  g_qm[b * BATCH + i] = M;
  g_qs[b * BATCH + i] = S;
}

// K4b: chunk combine + margins (min/max of norms) + target-logit fixup +
// weighted mean.
__global__ void k4b(const float* __restrict__ wts, float* __restrict__ out) {
  int i = threadIdx.x;  // 512
  float M = -1e30f, S = 0.0f;
  #pragma unroll
  for (int t = 0; t < NK4; ++t) {
    float m2 = g_qm[t * BATCH + i];
    float s2 = g_qs[t * BATCH + i];
    float nM = fmaxf(M, m2);
    S = S * __expf(M - nM) + s2 * __expf(m2 - nM);
    M = nM;
  }
  float n = g_norms[i];
  __shared__ float smin[512], smax[512];
  smin[i] = n; smax[i] = n;
  __syncthreads();
  for (int st = 256; st > 0; st >>= 1) {
    if (i < st) {
      smin[i] = fminf(smin[i], smin[i + st]);
      smax[i] = fmaxf(smax[i], smax[i + st]);
    }
    __syncthreads();
  }
  float lo = smin[0], hi = smax[0];
  float denom = fmaxf(hi - lo, 1e-8f);
  float mg = MMIN_ + (M0_ - MMIN_) * (n - lo) / denom;
  mg = fminf(fmaxf(mg, MMIN_), M0_);

  const float CLIP = 1.0f - 1e-7f;
  float wn = fmaxf(sqrtf(g_wn2[i]), 1e-12f);
  float ct = g_dot[i] / (fmaxf(n, 1e-12f) * wn);
  ct = fminf(fmaxf(ct, -CLIP), CLIP);

  float sint = sqrtf(fmaxf(0.0f, 1.0f - ct * ct));
  float cosm = ct * cosf(mg) - sint * sinf(mg);
  float lt_old = SCALE_ * ct, lt_new = SCALE_ * cosm;
  float S2 = S - __expf(lt_old - M) + __expf(lt_new - M);
  float lse = M + logf(S2);
  float contrib = (lse - lt_new) * wts[i];
  __shared__ float sred[512];
  sred[i] = contrib;
  __syncthreads();
  for (int st = 256; st > 0; st >>= 1) {
    if (i < st) sred[i] += sred[i + st];
    __syncthreads();
  }
  if (i == 0) out[0] = sred[0] * (1.0f / (float)BATCH);
}

extern "C" void kernel_launch(void* const* d_in, const int* in_sizes, int n_in,
                              void* d_out, int out_size, void* d_ws, size_t ws_size,
                              hipStream_t stream) {
  const float* feat = (const float*)d_in[0];
  const float* wmat = (const float*)d_in[1];
  const float* wts  = (const float*)d_in[2];
  const void*  labs = d_in[3];
  float* out = (float*)d_out;

  hipLaunchKernelGGL(k1a, dim3(BATCH / 4), dim3(256), 0, stream, feat, (const int*)labs);
  hipLaunchKernelGGL(k2c, dim3(BATCH / 4), dim3(256), 0, stream, feat, wmat, labs);
  hipLaunchKernelGGL(k3,  dim3(NBLK), dim3(512), 0, stream, wmat);
  hipLaunchKernelGGL(k4a, dim3(NK4), dim3(512), 0, stream);
  hipLaunchKernelGGL(k4b, dim3(1), dim3(512), 0, stream, wts, out);
}